// Round 2
// baseline (423.560 us; speedup 1.0000x reference)
//
#include <hip/hip_runtime.h>
#include <cstdint>
#include <cstddef>

#define NN 4096
#define CC 256
#define GG 50
#define PB 32
#define JD 384

#define O_OUT1 819200
#define O_OUT2 1638400
#define O_OUT3 68747264
#define O_OUT4 68763648

__device__ __forceinline__ unsigned bf16b(float f) {
    unsigned u = __float_as_uint(f);
    return (u + 0x7FFFu + ((u >> 16) & 1u)) >> 16;   // RNE f32->bf16
}
__device__ __forceinline__ float bf16f(short s) {
    return __uint_as_float(((unsigned)(unsigned short)s) << 16);
}

// ------------- k_proj: per 32 points, compute 384 fp32 proj dims (sim|sem|conf), ----------
// ------------- then seg softmax (via h_sem@Wseg), conf sigmoid, bf16 Fsim to ws ----------
__global__ __launch_bounds__(256) void k_proj(
    const float* __restrict__ x,
    const float* __restrict__ Wsem, const float* __restrict__ bsem,
    const float* __restrict__ Wseg, const float* __restrict__ bseg,
    const float* __restrict__ Wsim, const float* __restrict__ bsim,
    const float* __restrict__ Wconf, const float* __restrict__ bconf,
    const float* __restrict__ Wcl, const float* __restrict__ bcl,
    unsigned* __restrict__ fsimu,
    float* __restrict__ out0, float* __restrict__ out1,
    float* __restrict__ out3, float* __restrict__ out4)
{
    __shared__ float smem[15360];          // xs [256][36]=9216 | wch [16][384]=6144
    __shared__ float confl[PB], mxs[PB], sms[PB];

    float* xs  = smem;                     // x tile transposed [k][p], stride 36
    float* wch = smem + 9216;              // weight k-chunk [16][384]

    int t = threadIdx.x;
    int pbase = blockIdx.x * PB;
    if (t < PB) confl[t] = 0.f;

    #pragma unroll 4
    for (int p = 0; p < PB; ++p)
        xs[t * 36 + p] = x[(size_t)(pbase + p) * CC + t];     // coalesced over t

    int tj = t & 31, tp = t >> 5;          // tj: 32 groups of 12 dims; tp: 8 groups of 4 pts
    float acc[4][12];
    #pragma unroll
    for (int pp = 0; pp < 4; ++pp)
        #pragma unroll
        for (int jj = 0; jj < 12; ++jj) acc[pp][jj] = 0.f;

    for (int kc = 0; kc < 16; ++kc) {
        __syncthreads();
        #pragma unroll
        for (int i = 0; i < 8; ++i) {      // stage 16 x 384 weight chunk (3 matrices)
            int idx = i * 256 + t;
            int k = idx >> 7, jj = idx & 127;
            int g = (kc * 16 + k) * 128 + jj;
            wch[k * JD +       jj] = Wsim[g];
            wch[k * JD + 128 + jj] = Wsem[g];
            wch[k * JD + 256 + jj] = Wconf[g];
        }
        __syncthreads();
        #pragma unroll
        for (int k = 0; k < 16; ++k) {
            const float* xp = &xs[(kc * 16 + k) * 36 + tp * 4];
            float a0 = xp[0], a1 = xp[1], a2 = xp[2], a3 = xp[3];
            const float* wr = &wch[k * JD + tj * 12];
            #pragma unroll
            for (int jj = 0; jj < 12; ++jj) {
                float w = wr[jj];
                acc[0][jj] = fmaf(a0, w, acc[0][jj]);
                acc[1][jj] = fmaf(a1, w, acc[1][jj]);
                acc[2][jj] = fmaf(a2, w, acc[2][jj]);
                acc[3][jj] = fmaf(a3, w, acc[3][jj]);
            }
        }
    }
    __syncthreads();

    // ---- epilogue overlays (xs/wch dead) ----
    float* hsem = smem;                    // [32][132]
    float* WsT  = smem + 4224;             // [50][132] (Wseg transposed)
    float* segl = smem + 10824;            // [32][52]

    for (int i = t; i < GG * 128; i += 256) {     // stage Wseg^T
        int g = i >> 7, d = i & 127;
        WsT[g * 132 + d] = Wseg[d * GG + g];
    }

    #pragma unroll
    for (int pp = 0; pp < 4; ++pp) {
        int p = tp * 4 + pp;
        float vv[12];
        #pragma unroll
        for (int jj = 0; jj < 12; ++jj) {
            int j = tj * 12 + jj;
            float bb = (j < 128) ? bsim[j] : (j < 256 ? bsem[j - 128] : bconf[j - 256]);
            vv[jj] = acc[pp][jj] + bb;
        }
        #pragma unroll
        for (int jj = 0; jj < 12; jj += 2) {       // sim -> bf16 pairs to global ws
            int j = tj * 12 + jj;
            if (j < 128)
                fsimu[(size_t)(pbase + p) * 64 + (j >> 1)] =
                    bf16b(vv[jj]) | (bf16b(vv[jj + 1]) << 16);
        }
        #pragma unroll
        for (int jj = 0; jj < 12; ++jj) {          // sem -> LDS
            int j = tj * 12 + jj;
            if (j >= 128 && j < 256) hsem[p * 132 + (j - 128)] = vv[jj];
        }
        float c = 0.f;                              // conf partial dot with Wcl
        #pragma unroll
        for (int jj = 0; jj < 12; ++jj) {
            int j = tj * 12 + jj;
            if (j >= 256) c = fmaf(vv[jj], Wcl[j - 256], c);
        }
        if (tj >= 21) atomicAdd(&confl[p], c);
    }
    __syncthreads();

    for (int i = t; i < PB * GG; i += 256) {        // stage 2: seg logits
        int p = i / GG, g = i - p * GG;
        const float4* hp = (const float4*)&hsem[p * 132];
        const float4* wp = (const float4*)&WsT[g * 132];
        float a = bseg[g];
        #pragma unroll 8
        for (int d = 0; d < 32; ++d) {
            float4 h = hp[d], w = wp[d];
            a = fmaf(h.x, w.x, a); a = fmaf(h.y, w.y, a);
            a = fmaf(h.z, w.z, a); a = fmaf(h.w, w.w, a);
        }
        segl[p * 52 + g] = a;
    }
    __syncthreads();

    if (t < PB) {
        int p = t;
        float mx = -1e30f;
        for (int g = 0; g < GG; ++g) mx = fmaxf(mx, segl[p * 52 + g]);
        float s = 0.f;
        for (int g = 0; g < GG; ++g) s += __expf(segl[p * 52 + g] - mx);
        mxs[p] = mx; sms[p] = 1.f / s;
        float cl = confl[p] + bcl[0];
        out4[pbase + p] = cl;
        out3[pbase + p] = 1.f / (1.f + __expf(-cl));
    }
    __syncthreads();

    for (int i = t; i < PB * GG; i += 256) {
        int p = i / GG, g = i - p * GG;
        float l = segl[p * 52 + g];
        size_t o = (size_t)(pbase + p) * GG + g;
        out1[o] = l;
        out0[o] = __expf(l - mxs[p]) * sms[p];
    }
}

// ------------- k_simmat: out2 = relu(10*(r_i - 2*F F^T + r_j)), r from bf16 frags ---------
typedef short short8 __attribute__((ext_vector_type(8)));
typedef float f32x4 __attribute__((ext_vector_type(4)));

__global__ __launch_bounds__(256) void k_simmat(
    const short* __restrict__ fs, float* __restrict__ out2)
{
    int t = threadIdx.x;
    int lane = t & 63, wv = t >> 6;
    int b = blockIdx.z;
    int J = blockIdx.x * 128 + (wv & 1) * 64;
    int I = blockIdx.y * 128 + (wv >> 1) * 64;
    int rowl = lane & 15, quad = lane >> 4;

    const short8* F = (const short8*)(fs + (size_t)b * NN * 128);  // row = 16 short8

    f32x4 acc[4][4];
    #pragma unroll
    for (int r = 0; r < 4; ++r)
        #pragma unroll
        for (int c = 0; c < 4; ++c) { f32x4 z = {0.f,0.f,0.f,0.f}; acc[r][c] = z; }
    float sra[4] = {0.f,0.f,0.f,0.f}, srb[4] = {0.f,0.f,0.f,0.f};

    #pragma unroll
    for (int s = 0; s < 4; ++s) {
        short8 av[4], bv[4];
        #pragma unroll
        for (int r = 0; r < 4; ++r)
            av[r] = F[(size_t)(I + r * 16 + rowl) * 16 + s * 4 + quad];
        #pragma unroll
        for (int c = 0; c < 4; ++c)
            bv[c] = F[(size_t)(J + c * 16 + rowl) * 16 + s * 4 + quad];
        #pragma unroll
        for (int r = 0; r < 4; ++r)
            #pragma unroll
            for (int e = 0; e < 8; ++e) {
                float f = bf16f(av[r][e]); sra[r] = fmaf(f, f, sra[r]);
            }
        #pragma unroll
        for (int c = 0; c < 4; ++c)
            #pragma unroll
            for (int e = 0; e < 8; ++e) {
                float f = bf16f(bv[c][e]); srb[c] = fmaf(f, f, srb[c]);
            }
        #pragma unroll
        for (int r = 0; r < 4; ++r)
            #pragma unroll
            for (int c = 0; c < 4; ++c)
                acc[r][c] = __builtin_amdgcn_mfma_f32_16x16x32_bf16(av[r], bv[c], acc[r][c], 0, 0, 0);
    }

    // reduce partial sums across the 4 quads (lanes rowl, rowl+16, +32, +48)
    #pragma unroll
    for (int r = 0; r < 4; ++r) {
        sra[r] += __shfl_xor(sra[r], 16);
        sra[r] += __shfl_xor(sra[r], 32);
    }
    #pragma unroll
    for (int c = 0; c < 4; ++c) {
        srb[c] += __shfl_xor(srb[c], 16);
        srb[c] += __shfl_xor(srb[c], 32);
    }
    float riq[4][4];
    #pragma unroll
    for (int r = 0; r < 4; ++r)
        #pragma unroll
        for (int e = 0; e < 4; ++e)
            riq[r][e] = __shfl(sra[r], quad * 4 + e);     // r for row I + r*16 + quad*4 + e

    float* ob = out2 + (size_t)b * NN * NN;
    #pragma unroll
    for (int r = 0; r < 4; ++r) {
        int rbase = I + r * 16 + quad * 4;
        #pragma unroll
        for (int c = 0; c < 4; ++c) {
            int col = J + c * 16 + rowl;
            float rj = srb[c];
            f32x4 v = acc[r][c];
            #pragma unroll
            for (int e = 0; e < 4; ++e) {
                float dv = 10.f * (riq[r][e] + rj) - 20.f * v[e];
                ob[(size_t)(rbase + e) * NN + col] = fmaxf(dv, 0.f);
            }
        }
    }
}

extern "C" void kernel_launch(void* const* d_in, const int* in_sizes, int n_in,
                              void* d_out, int out_size, void* d_ws, size_t ws_size,
                              hipStream_t stream)
{
    const float* x     = (const float*)d_in[0];
    const float* Wsem  = (const float*)d_in[1];
    const float* bsem  = (const float*)d_in[2];
    const float* Wseg  = (const float*)d_in[3];
    const float* bseg  = (const float*)d_in[4];
    const float* Wsim  = (const float*)d_in[5];
    const float* bsim  = (const float*)d_in[6];
    const float* Wconf = (const float*)d_in[7];
    const float* bconf = (const float*)d_in[8];
    const float* Wcl   = (const float*)d_in[9];
    const float* bcl   = (const float*)d_in[10];

    // scratch: ONLY Fsim bf16, 16384*128*2 = 4,194,304 B — fits exactly in 4 MiB
    if (ws_size < (size_t)4 * NN * 128 * 2) return;   // refuse to overrun d_ws
    unsigned* fsim = (unsigned*)d_ws;

    float* out  = (float*)d_out;
    float* out0 = out;
    float* out1 = out + O_OUT1;
    float* out2 = out + O_OUT2;
    float* out3 = out + O_OUT3;
    float* out4 = out + O_OUT4;

    hipLaunchKernelGGL(k_proj, dim3(512), dim3(256), 0, stream,
                       x, Wsem, bsem, Wseg, bseg, Wsim, bsim, Wconf, bconf, Wcl, bcl,
                       fsim, out0, out1, out3, out4);
    hipLaunchKernelGGL(k_simmat, dim3(32, 32, 4), dim3(256), 0, stream,
                       (const short*)fsim, out2);
}